// Round 3
// baseline (322.595 us; speedup 1.0000x reference)
//
#include <hip/hip_runtime.h>

typedef _Float16 f16;
typedef f16 f16x2 __attribute__((ext_vector_type(2)));
typedef f16 f16x4 __attribute__((ext_vector_type(4)));
typedef f16 f16x8 __attribute__((ext_vector_type(8)));
typedef float f32x4 __attribute__((ext_vector_type(4)));

constexpr int Mdim = 32768, Ndim = 1024, Kdim = 1024;
constexpr int BM = 128, BN = 128, BK = 64;
constexpr int NT = Kdim / BK;   // 16 K-steps (even -> clean unroll-by-2)

static __device__ inline f16x2 cvt2(float a, float b) {
    return __builtin_bit_cast(f16x2, __builtin_amdgcn_cvt_pkrtz(a, b));
}

// out[b,n] = fp32(sum_k fp16(x[b,k]) * fp16(w[n,k])) + bias[n]
// (reference's early-termination mask is always-true: tstat >= 0 > TAU never holds)
__global__ __launch_bounds__(256, 2)
void etrow_gemm(const float* __restrict__ X, const float* __restrict__ W,
                const float* __restrict__ bias, float* __restrict__ out)
{
    __shared__ f16 As[2][BM * BK];   // 16 KB/buf, XOR-swizzled rows
    __shared__ f16 Bs[2][BN * BK];

    // bijective XCD-aware swizzle (nwg = 2048, divisible by 8)
    const int bid = blockIdx.x;
    const int cpx = gridDim.x >> 3;
    const int wg  = (bid & 7) * cpx + (bid >> 3);
    const int mIdx = wg >> 3;        // Ndim/BN == 8 n-tiles, n fastest
    const int nIdx = wg & 7;

    const int tid  = threadIdx.x;
    const int lane = tid & 63;
    const int wave = tid >> 6;
    const int wr   = (wave >> 1) * 64;
    const int wc   = (wave & 1) * 64;

    const int r0 = tid >> 4;    // 0..15 — staging row within 16-row pass
    const int c4 = tid & 15;    // which float4 of the 64-wide K slab

    const float* Xb = X + (size_t)mIdx * BM * Kdim;
    const float* Wb = W + (size_t)nIdx * BN * Kdim;

    // two named register sets (depth-2 prefetch; static indexing only)
    float4 aA[8], bA[8], aB[8], bB[8];
    f32x4 acc[4][4] = {};

    auto loadTo = [&](int kt, float4* ar, float4* br) {
        const float* xa = Xb + kt * BK + c4 * 4;
        const float* wb = Wb + kt * BK + c4 * 4;
        #pragma unroll
        for (int p = 0; p < 8; ++p) {
            const int r = p * 16 + r0;
            ar[p] = *(const float4*)(xa + r * Kdim);
            br[p] = *(const float4*)(wb + r * Kdim);
        }
    };

    auto writeFrom = [&](int buf, const float4* ar, const float4* br) {
        #pragma unroll
        for (int p = 0; p < 8; ++p) {
            const int r = p * 16 + r0;
            const int byte = (r * (BK * 2) + c4 * 8) ^ ((r & 7) << 4);
            f16x2 lo = cvt2(ar[p].x, ar[p].y);
            f16x2 hi = cvt2(ar[p].z, ar[p].w);
            *(f16x4*)((char*)(&As[buf][0]) + byte) =
                __builtin_shufflevector(lo, hi, 0, 1, 2, 3);
            lo = cvt2(br[p].x, br[p].y);
            hi = cvt2(br[p].z, br[p].w);
            *(f16x4*)((char*)(&Bs[buf][0]) + byte) =
                __builtin_shufflevector(lo, hi, 0, 1, 2, 3);
        }
    };

    auto computeTile = [&](int buf) {
        #pragma unroll
        for (int s = 0; s < 2; ++s) {          // two K=32 sub-steps per BK=64
            f16x8 af[4], bf[4];
            const int kb = s * 64 + (lane >> 4) * 16;  // byte offset in row
            #pragma unroll
            for (int m = 0; m < 4; ++m) {
                const int r = wr + m * 16 + (lane & 15);
                const int byte = (r * (BK * 2) + kb) ^ ((r & 7) << 4);
                af[m] = *(const f16x8*)((const char*)(&As[buf][0]) + byte);
            }
            #pragma unroll
            for (int n = 0; n < 4; ++n) {
                const int r = wc + n * 16 + (lane & 15);
                const int byte = (r * (BK * 2) + kb) ^ ((r & 7) << 4);
                bf[n] = *(const f16x8*)((const char*)(&Bs[buf][0]) + byte);
            }
            #pragma unroll
            for (int m = 0; m < 4; ++m)
                #pragma unroll
                for (int n = 0; n < 4; ++n)
                    acc[m][n] = __builtin_amdgcn_mfma_f32_16x16x32_f16(
                        af[m], bf[n], acc[m][n], 0, 0, 0);
        }
    };

    // prologue: tiles 0 and 1 in flight; tile 0 staged
    loadTo(0, aA, bA);
    loadTo(1, aB, bB);
    writeFrom(0, aA, bA);          // vmcnt counts past tile-1 loads (reg dep)
    __syncthreads();

    for (int t = 0; t < NT; t += 2) {
        // ---- even half: compute buf0 (tile t) ----
        if (t + 2 < NT) loadTo(t + 2, aA, bA);   // issue first: max latency cover
        computeTile(0);
        if (t + 1 < NT) writeFrom(1, aB, bB);    // tile t+1 -> buf1
        __syncthreads();
        // ---- odd half: compute buf1 (tile t+1) ----
        if (t + 3 < NT) loadTo(t + 3, aB, bB);
        computeTile(1);
        if (t + 2 < NT) writeFrom(0, aA, bA);    // tile t+2 -> buf0
        __syncthreads();
    }

    // epilogue: C/D layout col = lane&15, row = (lane>>4)*4 + reg (m89-verified)
    const int col0  = nIdx * BN + wc + (lane & 15);
    const int rbase = mIdx * BM + wr + (lane >> 4) * 4;
    float bv[4];
    #pragma unroll
    for (int n = 0; n < 4; ++n) bv[n] = bias[col0 + n * 16];

    #pragma unroll
    for (int m = 0; m < 4; ++m) {
        #pragma unroll
        for (int j = 0; j < 4; ++j) {
            const int row = rbase + m * 16 + j;
            float* o = out + (size_t)row * Ndim + col0;
            #pragma unroll
            for (int n = 0; n < 4; ++n)
                o[n * 16] = acc[m][n][j] + bv[n];
        }
    }
}

extern "C" void kernel_launch(void* const* d_in, const int* in_sizes, int n_in,
                              void* d_out, int out_size, void* d_ws, size_t ws_size,
                              hipStream_t stream) {
    const float* X  = (const float*)d_in[0];
    const float* W  = (const float*)d_in[1];
    const float* bs = (const float*)d_in[2];
    float* out = (float*)d_out;
    const int grid = (Mdim / BM) * (Ndim / BN);   // 2048 blocks
    etrow_gemm<<<grid, 256, 0, stream>>>(X, W, bs, out);
}

// Round 4
// 126.037 us; speedup vs baseline: 2.5595x; 2.5595x over previous
//
#include <hip/hip_runtime.h>

typedef _Float16 f16;
typedef f16 f16x2 __attribute__((ext_vector_type(2)));
typedef f16 f16x4 __attribute__((ext_vector_type(4)));
typedef f16 f16x8 __attribute__((ext_vector_type(8)));
typedef float f32x4 __attribute__((ext_vector_type(4)));

constexpr int Mdim = 32768, Ndim = 1024, Kdim = 1024;
constexpr int BM = 128, BN = 128, BK = 64;
constexpr int NT = Kdim / BK;   // 16 K-steps

static __device__ inline f16x2 cvt2(float a, float b) {
    return __builtin_bit_cast(f16x2, __builtin_amdgcn_cvt_pkrtz(a, b));
}
static __device__ inline f16x4 cvt4(float4 v) {
    f16x2 lo = cvt2(v.x, v.y), hi = cvt2(v.z, v.w);
    return __builtin_shufflevector(lo, hi, 0, 1, 2, 3);
}

// out[b,n] = fp32(sum_k fp16(x[b,k]) * fp16(w[n,k])) + bias[n]
// (reference's early-termination mask is always-true: tstat >= 0 > TAU never holds)
//
// Pipeline (per iter t): cvt(t+1) [loads are 1 iter old -> ~free wait]
//   -> issue loads(t+2) into the SAME fp32 regs (WAR pins order, no spill)
//   -> MFMA on buf(t&1) -> ds_write tile t+1 -> barrier.
__global__ __launch_bounds__(256, 2)
void etrow_gemm(const float* __restrict__ X, const float* __restrict__ W,
                const float* __restrict__ bias, float* __restrict__ out)
{
    __shared__ f16 As[2][BM * BK];   // 16 KB/buf, XOR-swizzled rows (0 conflicts, R2-verified)
    __shared__ f16 Bs[2][BN * BK];

    // bijective XCD-aware swizzle (nwg = 2048, divisible by 8)
    const int bid = blockIdx.x;
    const int cpx = gridDim.x >> 3;
    const int wg  = (bid & 7) * cpx + (bid >> 3);
    const int mIdx = wg >> 3;        // Ndim/BN == 8 n-tiles, n fastest
    const int nIdx = wg & 7;

    const int tid  = threadIdx.x;
    const int lane = tid & 63;
    const int wave = tid >> 6;
    const int wr   = (wave >> 1) * 64;
    const int wc   = (wave & 1) * 64;

    const int r0 = tid >> 4;    // 0..15 — staging row within 16-row pass
    const int c4 = tid & 15;    // which float4 of the 64-wide K slab

    const float* Xb = X + (size_t)mIdx * BM * Kdim;
    const float* Wb = W + (size_t)nIdx * BN * Kdim;

    float4 a32[8], b32[8];      // ONE fp32 in-flight set (64 VGPR)
    f16x4  a16[8], b16[8];      // converted, awaiting ds_write (32 VGPR)
    f32x4  acc[4][4] = {};

    auto loadTo = [&](int kt) {
        const float* xa = Xb + kt * BK + c4 * 4;
        const float* wb = Wb + kt * BK + c4 * 4;
        #pragma unroll
        for (int p = 0; p < 8; ++p) {
            const int r = p * 16 + r0;
            a32[p] = *(const float4*)(xa + r * Kdim);
            b32[p] = *(const float4*)(wb + r * Kdim);
        }
    };

    auto convert = [&]() {
        #pragma unroll
        for (int p = 0; p < 8; ++p) {
            a16[p] = cvt4(a32[p]);
            b16[p] = cvt4(b32[p]);
        }
    };

    auto writeTiles = [&](int buf) {
        #pragma unroll
        for (int p = 0; p < 8; ++p) {
            const int r = p * 16 + r0;
            const int byte = (r * (BK * 2) + c4 * 8) ^ ((r & 7) << 4);
            *(f16x4*)((char*)(&As[buf][0]) + byte) = a16[p];
            *(f16x4*)((char*)(&Bs[buf][0]) + byte) = b16[p];
        }
    };

    auto computeTile = [&](int buf) {
        #pragma unroll
        for (int s = 0; s < 2; ++s) {          // two K=32 sub-steps per BK=64
            f16x8 af[4], bf[4];
            const int kb = s * 64 + (lane >> 4) * 16;  // byte offset in row
            #pragma unroll
            for (int m = 0; m < 4; ++m) {
                const int r = wr + m * 16 + (lane & 15);
                const int byte = (r * (BK * 2) + kb) ^ ((r & 7) << 4);
                af[m] = *(const f16x8*)((const char*)(&As[buf][0]) + byte);
            }
            #pragma unroll
            for (int n = 0; n < 4; ++n) {
                const int r = wc + n * 16 + (lane & 15);
                const int byte = (r * (BK * 2) + kb) ^ ((r & 7) << 4);
                bf[n] = *(const f16x8*)((const char*)(&Bs[buf][0]) + byte);
            }
            #pragma unroll
            for (int m = 0; m < 4; ++m)
                #pragma unroll
                for (int n = 0; n < 4; ++n)
                    acc[m][n] = __builtin_amdgcn_mfma_f32_16x16x32_f16(
                        af[m], bf[n], acc[m][n], 0, 0, 0);
        }
    };

    // prologue: tile0 loaded+converted+staged; tile1 loads in flight
    loadTo(0);
    convert();          // one cold vmcnt stall (unavoidable, once)
    loadTo(1);
    writeTiles(0);
    __syncthreads();

    #pragma unroll
    for (int t = 0; t < NT; ++t) {
        if (t + 1 < NT) convert();            // tile t+1: loads 1 iter old -> cheap
        if (t + 2 < NT) loadTo(t + 2);        // reuse freed fp32 regs (WAR-ordered)
        computeTile(t & 1);
        if (t + 1 < NT) writeTiles((t + 1) & 1);
        __syncthreads();
    }

    // epilogue: C/D layout col = lane&15, row = (lane>>4)*4 + reg (m89-verified)
    const int col0  = nIdx * BN + wc + (lane & 15);
    const int rbase = mIdx * BM + wr + (lane >> 4) * 4;
    float bv[4];
    #pragma unroll
    for (int n = 0; n < 4; ++n) bv[n] = bias[col0 + n * 16];

    #pragma unroll
    for (int m = 0; m < 4; ++m) {
        #pragma unroll
        for (int j = 0; j < 4; ++j) {
            const int row = rbase + m * 16 + j;
            float* o = out + (size_t)row * Ndim + col0;
            #pragma unroll
            for (int n = 0; n < 4; ++n)
                o[n * 16] = acc[m][n][j] + bv[n];
        }
    }
}

extern "C" void kernel_launch(void* const* d_in, const int* in_sizes, int n_in,
                              void* d_out, int out_size, void* d_ws, size_t ws_size,
                              hipStream_t stream) {
    const float* X  = (const float*)d_in[0];
    const float* W  = (const float*)d_in[1];
    const float* bs = (const float*)d_in[2];
    float* out = (float*)d_out;
    const int grid = (Mdim / BM) * (Ndim / BN);   // 2048 blocks
    etrow_gemm<<<grid, 256, 0, stream>>>(X, W, bs, out);
}

// Round 5
// 96.744 us; speedup vs baseline: 3.3345x; 1.3028x over previous
//
#include <hip/hip_runtime.h>

typedef _Float16 f16;
typedef f16 f16x2 __attribute__((ext_vector_type(2)));
typedef f16 f16x4 __attribute__((ext_vector_type(4)));
typedef f16 f16x8 __attribute__((ext_vector_type(8)));
typedef float f32x4 __attribute__((ext_vector_type(4)));

constexpr int Mdim = 32768, Ndim = 1024, Kdim = 1024;
constexpr int BM = 256, BN = 256, BK = 64;
constexpr int NT = Kdim / BK;   // 16 K-steps

static __device__ inline f16x2 cvt2(float a, float b) {
    return __builtin_bit_cast(f16x2, __builtin_amdgcn_cvt_pkrtz(a, b));
}
static __device__ inline f16x4 cvt4(float4 v) {
    f16x2 lo = cvt2(v.x, v.y), hi = cvt2(v.z, v.w);
    return __builtin_shufflevector(lo, hi, 0, 1, 2, 3);
}

// out[b,n] = fp32(sum_k fp16(x[b,k]) * fp16(w[n,k])) + bias[n]
// (reference's early-termination mask is always-true: tstat >= 0 > TAU never holds)
//
// 256x256 tile: halves cache read traffic vs 128^2 (2.1 -> 1.07 GB) — R2/R4
// showed ~17 TB/s aggregate cache-BW ceiling. One shared staging reg set S[8]
// time-shared A->B to stay under 256 VGPRs (R3 spill lesson).
__global__ __launch_bounds__(512, 2)
void etrow_gemm(const float* __restrict__ X, const float* __restrict__ W,
                const float* __restrict__ bias, float* __restrict__ out)
{
    __shared__ f16 As[2][BM * BK];   // 32 KB per buffer
    __shared__ f16 Bs[2][BN * BK];   // 128 KB total -> 1 block/CU

    // bijective XCD-aware swizzle (512 blocks, 64 per XCD)
    const int bid = blockIdx.x;
    const int cpx = gridDim.x >> 3;
    const int wg  = (bid & 7) * cpx + (bid >> 3);
    const int mIdx = wg >> 2;        // Ndim/BN == 4 n-tiles, n fastest
    const int nIdx = wg & 3;

    const int tid  = threadIdx.x;
    const int lane = tid & 63;
    const int wave = tid >> 6;       // 0..7
    const int wr   = (wave >> 2) * 128;   // 2 m-waves: wave tile 128x64
    const int wc   = (wave & 3) * 64;     // 4 n-waves

    const int r0 = tid >> 4;    // 0..31 — staging row within 32-row pass
    const int c4 = tid & 15;    // which float4 of the 64-wide K slab

    const float* Xb = X + (size_t)mIdx * BM * Kdim;
    const float* Wb = W + (size_t)nIdx * BN * Kdim;

    float4 S[8];                 // single in-flight fp32 set, time-shared A/B
    f32x4 acc[8][4] = {};

    auto loadA = [&](int kt) {
        const float* xa = Xb + kt * BK + c4 * 4;
        #pragma unroll
        for (int p = 0; p < 8; ++p)
            S[p] = *(const float4*)(xa + (p * 32 + r0) * Kdim);
    };
    auto loadB = [&](int kt) {
        const float* wb = Wb + kt * BK + c4 * 4;
        #pragma unroll
        for (int p = 0; p < 8; ++p)
            S[p] = *(const float4*)(wb + (p * 32 + r0) * Kdim);
    };
    auto cvtWrite = [&](f16* lds) {   // consume S -> f16 LDS (frees S)
        #pragma unroll
        for (int p = 0; p < 8; ++p) {
            const int r = p * 32 + r0;
            const int byte = (r * (BK * 2) + c4 * 8) ^ ((r & 7) << 4);
            *(f16x4*)((char*)lds + byte) = cvt4(S[p]);
        }
    };

    auto computeSub = [&](const f16* Ab, const f16* Bb, int s) {
        f16x8 af[8], bf[4];
        const int kb = s * 64 + (lane >> 4) * 16;   // byte offset in row
        #pragma unroll
        for (int i = 0; i < 8; ++i) {
            const int r = wr + i * 16 + (lane & 15);
            const int byte = (r * (BK * 2) + kb) ^ ((r & 7) << 4);
            af[i] = *(const f16x8*)((const char*)Ab + byte);
        }
        #pragma unroll
        for (int j = 0; j < 4; ++j) {
            const int r = wc + j * 16 + (lane & 15);
            const int byte = (r * (BK * 2) + kb) ^ ((r & 7) << 4);
            bf[j] = *(const f16x8*)((const char*)Bb + byte);
        }
        #pragma unroll
        for (int i = 0; i < 8; ++i)
            #pragma unroll
            for (int j = 0; j < 4; ++j)
                acc[i][j] = __builtin_amdgcn_mfma_f32_16x16x32_f16(
                    af[i], bf[j], acc[i][j], 0, 0, 0);
    };

    // prologue: tile 0 staged; A(1) in flight across the barrier
    loadA(0); cvtWrite(&As[0][0]);
    loadB(0); cvtWrite(&Bs[0][0]);
    loadA(1);
    __syncthreads();

    for (int t = 0; t < NT; ++t) {
        const int cur = t & 1, nxt = cur ^ 1;
        // A(t+1): loads are ~1 iteration old -> cheap wait; frees S
        if (t + 1 < NT) { cvtWrite(&As[nxt][0]); loadB(t + 1); }
        computeSub(&As[cur][0], &Bs[cur][0], 0);   // covers B(t+1) latency
        if (t + 1 < NT) { cvtWrite(&Bs[nxt][0]); }
        if (t + 2 < NT) { loadA(t + 2); }          // full-iteration leg for X
        computeSub(&As[cur][0], &Bs[cur][0], 1);
        __syncthreads();
    }

    // epilogue: C/D layout col = lane&15, row = (lane>>4)*4 + reg (m89-verified)
    const int col0  = nIdx * BN + wc + (lane & 15);
    const int rbase = mIdx * BM + wr + (lane >> 4) * 4;
    float bv[4];
    #pragma unroll
    for (int n = 0; n < 4; ++n) bv[n] = bias[col0 + n * 16];

    #pragma unroll
    for (int m = 0; m < 8; ++m) {
        #pragma unroll
        for (int j = 0; j < 4; ++j) {
            const int row = rbase + m * 16 + j;
            float* o = out + (size_t)row * Ndim + col0;
            #pragma unroll
            for (int n = 0; n < 4; ++n)
                o[n * 16] = acc[m][n][j] + bv[n];
        }
    }
}

extern "C" void kernel_launch(void* const* d_in, const int* in_sizes, int n_in,
                              void* d_out, int out_size, void* d_ws, size_t ws_size,
                              hipStream_t stream) {
    const float* X  = (const float*)d_in[0];
    const float* W  = (const float*)d_in[1];
    const float* bs = (const float*)d_in[2];
    float* out = (float*)d_out;
    const int grid = (Mdim / BM) * (Ndim / BN);   // 512 blocks
    etrow_gemm<<<grid, 512, 0, stream>>>(X, W, bs, out);
}